// Round 1
// baseline (78.603 us; speedup 1.0000x reference)
//
#include <hip/hip_runtime.h>
#include <math.h>

// MeanAggregator: time-decayed neighbor mean.
// Shapes: nodes[B], neigh_ids[B,K=32], neigh_times[B,K], features[N,D=128] fp32.
// out[B,D] = (F[nodes] + sum_j w_j F[neigh_j]) / denom, with
//   w_j = (t_j <= 100) ? exp((t_j-100)/100) : 0, normalized by T = (S==0?1:S),
//   denom = 1 + S/T  (== 2 when any valid neighbor, 1 otherwise).
//
// One 64-lane wave per output row; lane l owns feature dims {2l, 2l+1} (float2),
// so each gathered feature row is a single coalesced 512B wave transaction.
// w_k broadcast via __shfl is wave-uniform -> skip gather when w_k == 0
// (~half the neighbors), halving feature traffic.

__global__ __launch_bounds__(256) void mean_agg_kernel(
    const int*   __restrict__ nodes,        // [B]
    const int*   __restrict__ neigh_ids,    // [B,32]
    const float* __restrict__ neigh_times,  // [B,32]
    const float* __restrict__ features,     // [N,128]
    float*       __restrict__ out,          // [B,128]
    int B)
{
    const int wave = threadIdx.x >> 6;            // 4 waves / block
    const int lane = threadIdx.x & 63;
    const int row  = blockIdx.x * 4 + wave;
    if (row >= B) return;                          // wave-uniform exit

    const int j = lane & 31;                       // both halves mirror j=0..31
    const float t  = neigh_times[row * 32 + j];
    const int  idj = neigh_ids[row * 32 + j];
    float wj = (t <= 100.0f) ? __expf((t - 100.0f) * 0.01f) : 0.0f;

    // S = sum of w over the 32 neighbors (butterfly within each 32-half)
    float S = wj;
    #pragma unroll
    for (int m = 1; m < 32; m <<= 1)
        S += __shfl_xor(S, m);

    const float T     = (S == 0.0f) ? 1.0f : S;
    const float denom = 1.0f + S / T;

    // Weighted gather-accumulate: lane l handles dims 2l, 2l+1.
    float2 acc = make_float2(0.0f, 0.0f);
    #pragma unroll 4
    for (int k = 0; k < 32; ++k) {
        const float wk = __shfl(wj, k);            // wave-uniform
        if (wk != 0.0f) {
            const int idk = __shfl(idj, k);
            const float2 f = *reinterpret_cast<const float2*>(
                &features[(size_t)idk * 128 + lane * 2]);
            acc.x += wk * f.x;
            acc.y += wk * f.y;
        }
    }

    const int self = nodes[row];
    const float2 fs = *reinterpret_cast<const float2*>(
        &features[(size_t)self * 128 + lane * 2]);

    const float inv_d  = 1.0f / denom;
    const float inv_td = 1.0f / (T * denom);
    float2 o;
    o.x = fs.x * inv_d + acc.x * inv_td;
    o.y = fs.y * inv_d + acc.y * inv_td;
    *reinterpret_cast<float2*>(&out[(size_t)row * 128 + lane * 2]) = o;
}

extern "C" void kernel_launch(void* const* d_in, const int* in_sizes, int n_in,
                              void* d_out, int out_size, void* d_ws, size_t ws_size,
                              hipStream_t stream) {
    const int*   nodes       = (const int*)  d_in[0];
    const int*   neigh_ids   = (const int*)  d_in[1];
    const float* neigh_times = (const float*)d_in[2];
    const float* features    = (const float*)d_in[3];
    float*       out         = (float*)      d_out;

    const int B = in_sizes[0];                 // 50000
    const int rows_per_block = 4;              // 4 waves/block
    const int grid = (B + rows_per_block - 1) / rows_per_block;

    mean_agg_kernel<<<grid, 256, 0, stream>>>(nodes, neigh_ids, neigh_times,
                                              features, out, B);
}

// Round 2
// 72.412 us; speedup vs baseline: 1.0855x; 1.0855x over previous
//
#include <hip/hip_runtime.h>
#include <math.h>

// MeanAggregator: time-decayed neighbor mean.
// Shapes: nodes[B], neigh_ids[B,K=32], neigh_times[B,K], features[N,D=128] fp32.
// out[B,D] = (F[nodes] + sum_j w_j F[neigh_j]) / denom, with
//   w_j = (t_j <= 100) ? exp((t_j-100)/100) : 0,  S = sum w_j, T = (S==0?1:S),
//   denom = 1 + S/T.
//
// One 64-lane wave per output row, split into two 32-lane halves:
//   half h (lanes 32h..32h+31) processes neighbors k = 2i+h, i=0..15.
//   lane (half,c) owns dims 4c..4c+3 as a float4 -> each gathered row is one
//   coalesced 512B half-wave transaction (global_load_dwordx4), two rows in
//   flight per wave per iteration.
// w_k broadcast via __shfl is half-wave-uniform -> skip gather when w_k == 0
// (~half the neighbors), halving feature traffic.
// Final shfl_xor(32) combines the two halves' partial accumulators.

__global__ __launch_bounds__(256) void mean_agg_kernel(
    const int*   __restrict__ nodes,        // [B]
    const int*   __restrict__ neigh_ids,    // [B,32]
    const float* __restrict__ neigh_times,  // [B,32]
    const float* __restrict__ features,     // [N,128]
    float*       __restrict__ out,          // [B,128]
    int B)
{
    const int wave = threadIdx.x >> 6;            // 4 waves / block
    const int lane = threadIdx.x & 63;
    const int half = lane >> 5;                   // 0 or 1
    const int c    = lane & 31;                   // dim chunk: dims 4c..4c+3
    const int row  = blockIdx.x * 4 + wave;
    if (row >= B) return;                          // wave-uniform exit

    // Lanes l and l+32 mirror neighbor j = c.
    const float t  = neigh_times[row * 32 + c];
    const int  idj = neigh_ids[row * 32 + c];
    float wj = (t <= 100.0f) ? __expf((t - 100.0f) * 0.01f) : 0.0f;

    // S = sum of w over the 32 neighbors (butterfly within each 32-half)
    float S = wj;
    #pragma unroll
    for (int m = 1; m < 32; m <<= 1)
        S += __shfl_xor(S, m);

    const float T     = (S == 0.0f) ? 1.0f : S;
    const float denom = 1.0f + S / T;

    // Weighted gather-accumulate: half h takes neighbors 2i+h.
    float4 acc = make_float4(0.0f, 0.0f, 0.0f, 0.0f);
    #pragma unroll
    for (int i = 0; i < 16; ++i) {
        const int   k   = 2 * i + half;
        const float wk  = __shfl(wj, k);           // half-wave-uniform
        const int   idk = __shfl(idj, k);          // hoisted out of the branch
        if (wk != 0.0f) {
            const float4 f = *reinterpret_cast<const float4*>(
                &features[(size_t)idk * 128 + c * 4]);
            acc.x += wk * f.x;
            acc.y += wk * f.y;
            acc.z += wk * f.z;
            acc.w += wk * f.w;
        }
    }
    // Combine the two halves (each holds a disjoint neighbor subset, same dims).
    acc.x += __shfl_xor(acc.x, 32);
    acc.y += __shfl_xor(acc.y, 32);
    acc.z += __shfl_xor(acc.z, 32);
    acc.w += __shfl_xor(acc.w, 32);

    // Self row: both halves read the same 16B (HW broadcasts); 512B total.
    const int self = nodes[row];
    const float4 fs = *reinterpret_cast<const float4*>(
        &features[(size_t)self * 128 + c * 4]);

    const float inv_d  = 1.0f / denom;
    const float inv_td = 1.0f / (T * denom);
    float4 o;
    o.x = fs.x * inv_d + acc.x * inv_td;
    o.y = fs.y * inv_d + acc.y * inv_td;
    o.z = fs.z * inv_d + acc.z * inv_td;
    o.w = fs.w * inv_d + acc.w * inv_td;

    // One coalesced 512B store from the lower half-wave.
    if (half == 0)
        *reinterpret_cast<float4*>(&out[(size_t)row * 128 + c * 4]) = o;
}

extern "C" void kernel_launch(void* const* d_in, const int* in_sizes, int n_in,
                              void* d_out, int out_size, void* d_ws, size_t ws_size,
                              hipStream_t stream) {
    const int*   nodes       = (const int*)  d_in[0];
    const int*   neigh_ids   = (const int*)  d_in[1];
    const float* neigh_times = (const float*)d_in[2];
    const float* features    = (const float*)d_in[3];
    float*       out         = (float*)      d_out;

    const int B = in_sizes[0];                 // 50000
    const int rows_per_block = 4;              // 4 waves/block
    const int grid = (B + rows_per_block - 1) / rows_per_block;

    mean_agg_kernel<<<grid, 256, 0, stream>>>(nodes, neigh_ids, neigh_times,
                                              features, out, B);
}